// Round 1
// 1628.135 us; speedup vs baseline: 1.1474x; 1.1474x over previous
//
#include <hip/hip_runtime.h>

#define NEMB 1024
#define CDIM 256
#define NPOS 131072            // 32*64*64 positions
#define Z_ELEMS 33554432       // 32*256*64*64

// d_out is FLOAT32, flat layout [z_q | cl | cml | indices] (verified r0/r5).
#define SC_OFF  ((size_t)33554432)
#define IDX_OFF ((size_t)33554434)

typedef float f32x8 __attribute__((ext_vector_type(8)));

// Bitwise replication of numpy pairwise_sum of a[i]^2 over 256 floats with a
// stride: n=256 -> split 128+128; each 128-block uses 8 stride-8 accumulators
// combined ((r0+r1)+(r2+r3))+((r4+r5)+(r6+r7)). Squares are materialized
// (rounded) separately -> FP contraction OFF. Arithmetic order is identical
// to the previously verified contiguous helper.
__device__ __forceinline__ float np_pairwise_sq256_s(const float* a, int stride) {
#pragma clang fp contract(off)
  float s0, s1;
  {
    float r[8];
#pragma unroll
    for (int j = 0; j < 8; ++j) { float v = a[j * stride]; r[j] = v * v; }
#pragma unroll
    for (int i = 8; i < 128; i += 8) {
#pragma unroll
      for (int j = 0; j < 8; ++j) { float v = a[(i + j) * stride]; r[j] += v * v; }
    }
    s0 = ((r[0] + r[1]) + (r[2] + r[3])) + ((r[4] + r[5]) + (r[6] + r[7]));
  }
  {
    float r[8];
#pragma unroll
    for (int j = 0; j < 8; ++j) { float v = a[(128 + j) * stride]; r[j] = v * v; }
#pragma unroll
    for (int i = 8; i < 128; i += 8) {
#pragma unroll
      for (int j = 0; j < 8; ++j) { float v = a[(128 + i + j) * stride]; r[j] += v * v; }
    }
    s1 = ((r[0] + r[1]) + (r[2] + r[3])) + ((r[4] + r[5]) + (r[6] + r[7]));
  }
  return s0 + s1;
}

__global__ void vq_bsq(const float* __restrict__ cb, float* __restrict__ Bsq,
                       double* __restrict__ loss_acc) {
  int k = blockIdx.x * blockDim.x + threadIdx.x;
  if (k == 0) *loss_acc = 0.0;
  if (k < NEMB) Bsq[k] = np_pairwise_sq256_s(cb + (size_t)k * CDIM, 1);
}

// One 8-dim slice of the dot-product GEMM.
// zs: wave-uniform (readfirstlane'd) pointer to z at dim-base of this slice
//     -> dereferences become s_load_dwordx8 with immediate offsets.
// ea/eb: this lane's code values for dims [c..c+3] / [c+4..c+7] (VGPRs).
// acc[p] += sum_j z[c+j][p] * e[c+j], j ascending -> preserves the exact
// sequential-ascending-c fp32 FMA chain per (position, code).
__device__ __forceinline__ void vq_slice(const float* __restrict__ zs,
                                         const float4 ea, const float4 eb,
                                         float (&acc)[64]) {
#pragma unroll
  for (int pg = 0; pg < 8; ++pg) {
    {
      f32x8 z0 = *(const f32x8*)(zs + 0 * 4096 + pg * 8);
      f32x8 z1 = *(const f32x8*)(zs + 1 * 4096 + pg * 8);
      f32x8 z2 = *(const f32x8*)(zs + 2 * 4096 + pg * 8);
      f32x8 z3 = *(const f32x8*)(zs + 3 * 4096 + pg * 8);
#pragma unroll
      for (int i = 0; i < 8; ++i) {
        float a = acc[pg * 8 + i];
        a = __builtin_fmaf(z0[i], ea.x, a);
        a = __builtin_fmaf(z1[i], ea.y, a);
        a = __builtin_fmaf(z2[i], ea.z, a);
        a = __builtin_fmaf(z3[i], ea.w, a);
        acc[pg * 8 + i] = a;
      }
    }
    {
      f32x8 z4 = *(const f32x8*)(zs + 4 * 4096 + pg * 8);
      f32x8 z5 = *(const f32x8*)(zs + 5 * 4096 + pg * 8);
      f32x8 z6 = *(const f32x8*)(zs + 6 * 4096 + pg * 8);
      f32x8 z7 = *(const f32x8*)(zs + 7 * 4096 + pg * 8);
#pragma unroll
      for (int i = 0; i < 8; ++i) {
        float a = acc[pg * 8 + i];
        a = __builtin_fmaf(z4[i], eb.x, a);
        a = __builtin_fmaf(z5[i], eb.y, a);
        a = __builtin_fmaf(z6[i], eb.z, a);
        a = __builtin_fmaf(z7[i], eb.w, a);
        acc[pg * 8 + i] = a;
      }
    }
  }
}

// Inverted mapping: 1024 threads, lane k = tid = CODE index; acc[64] = one
// accumulator per position of the (b,h) tile. Codebook streams through
// per-lane VGPRs (double-buffered, latency hidden under compute); z streams
// through wave-uniform s_loads of a 2KB/slice hot set shared by 16 waves.
// LDS 72.7KB -> 8.7KB; occupancy VGPR-capped at 16 waves/CU (4/SIMD).
__global__ __launch_bounds__(1024, 4) void vq_main(
    const float* __restrict__ z, const float* __restrict__ cb,
    const float* __restrict__ Bsq, float* __restrict__ out,
    double* __restrict__ loss_acc) {
  __shared__ float A_lds[64];
  __shared__ float dmin_s[16][64];
  __shared__ int   kmin_s[16][64];
  __shared__ int   idx_s[64];
  __shared__ double wsum[16];

  const int tid = threadIdx.x;
  const int wv = tid >> 6;
  const int lane = tid & 63;
  const int bh = blockIdx.x;                       // b*64 + h
  const int zoff = ((bh >> 6) << 20) | ((bh & 63) << 6);  // b*CDIM*4096 + h*64

  // ||z||^2 per position (np pairwise order, stride 4096), wave 0 only;
  // lanes = w -> coalesced. One barrier; ~1.5us per block residency.
  if (tid < 64) A_lds[tid] = np_pairwise_sq256_s(z + zoff + tid, 4096);
  __syncthreads();

  float acc[64];
#pragma unroll
  for (int p = 0; p < 64; ++p) acc[p] = 0.0f;

  const float* cbk = cb + ((size_t)tid << 8);      // this lane's code row
  float4 ea0 = *(const float4*)(cbk + 0);
  float4 eb0 = *(const float4*)(cbk + 4);
  float4 ea1, eb1;

  for (int s = 0; s < 32; s += 2) {
    const int o1 = (s + 1) << 3;
    ea1 = *(const float4*)(cbk + o1);              // prefetch slice s+1
    eb1 = *(const float4*)(cbk + o1 + 4);
    {
      const int zo = __builtin_amdgcn_readfirstlane(zoff + (s << 15));
      vq_slice(z + zo, ea0, eb0, acc);             // compute slice s
    }
    const int o2 = (s + 2) < 32 ? (s + 2) << 3 : 0;  // clamp: avoid OOB tail
    ea0 = *(const float4*)(cbk + o2);              // prefetch slice s+2
    eb0 = *(const float4*)(cbk + o2 + 4);
    {
      const int zo = __builtin_amdgcn_readfirstlane(zoff + ((s + 1) << 15));
      vq_slice(z + zo, ea1, eb1, acc);             // compute slice s+1
    }
  }

  // d = fl(fl(A+B) - 2*C) exactly as the verified kernel (2*C exact, so a
  // contracted fma(-2,acc,A+B) is bitwise identical). Argmin over codes =
  // lexicographic (d, k) butterfly across lanes (lane order == k order),
  // then ascending-wave reduce -> numpy first-index tie semantics.
  const float Bk = Bsq[tid];
#pragma unroll
  for (int p = 0; p < 64; ++p) {
    float dm = (A_lds[p] + Bk) - 2.0f * acc[p];
    int km = tid;
#pragma unroll
    for (int m = 32; m; m >>= 1) {
      float d2 = __shfl_xor(dm, m);
      int k2 = __shfl_xor(km, m);
      if (d2 < dm || (d2 == dm && k2 < km)) { dm = d2; km = k2; }
    }
    if (lane == 0) { dmin_s[wv][p] = dm; kmin_s[wv][p] = km; }
  }
  __syncthreads();

  if (tid < 64) {
    float dm = dmin_s[0][tid];
    int km = kmin_s[0][tid];
#pragma unroll
    for (int v = 1; v < 16; ++v) {   // ascending wave = ascending k chunks
      float dv = dmin_s[v][tid];
      int kv = kmin_s[v][tid];
      if (dv < dm) { dm = dv; km = kv; }  // strict < : first-index ties
    }
    idx_s[tid] = km;
    out[IDX_OFF + (size_t)bh * 64 + tid] = (float)km;   // fp32 index
  }
  __syncthreads();

  // z_q = fl(z + fl(e - z)) fp32; loss = sum (e-z)^2 in double (order-safe).
  double lsum = 0.0;
#pragma unroll
  for (int i = tid; i < CDIM * 64; i += 1024) {
    const int c = i >> 6, w = i & 63;
    const float e = cb[((size_t)idx_s[w] << 8) + c];
    const float zz = z[zoff + (c << 12) + w];
    const float diff = e - zz;
    lsum += (double)diff * (double)diff;
    out[zoff + (c << 12) + w] = zz + diff;
  }
  for (int off = 32; off; off >>= 1) lsum += __shfl_down(lsum, off);
  if (lane == 0) wsum[wv] = lsum;
  __syncthreads();
  if (tid == 0) {
    double t = 0.0;
#pragma unroll
    for (int v = 0; v < 16; ++v) t += wsum[v];
    atomicAdd(loss_acc, t);
  }
}

__global__ void vq_finalize(const double* __restrict__ loss_acc,
                            float* __restrict__ out) {
  double m = *loss_acc / (double)Z_ELEMS;
  out[SC_OFF] = (float)m;
  out[SC_OFF + 1] = (float)(0.25 * m);
}

extern "C" void kernel_launch(void* const* d_in, const int* in_sizes, int n_in,
                              void* d_out, int out_size, void* d_ws,
                              size_t ws_size, hipStream_t stream) {
  (void)n_in; (void)ws_size; (void)out_size;
  const float* z;
  const float* cb;
  if (in_sizes[0] == Z_ELEMS) {
    z = (const float*)d_in[0];
    cb = (const float*)d_in[1];
  } else {
    z = (const float*)d_in[1];
    cb = (const float*)d_in[0];
  }
  float* out = (float*)d_out;
  double* loss = (double*)d_ws;                 // 8 bytes
  float* Bsq = (float*)((char*)d_ws + 256);     // 4 KB

  vq_bsq<<<dim3(16), dim3(64), 0, stream>>>(cb, Bsq, loss);
  vq_main<<<dim3(2048), dim3(1024), 0, stream>>>(z, cb, Bsq, out, loss);
  vq_finalize<<<dim3(1), dim3(1), 0, stream>>>(loss, out);
}